// Round 2
// baseline (159.683 us; speedup 1.0000x reference)
//
#include <hip/hip_runtime.h>

#define NSEG 21      // labels 0..20
#define NLBL 20
#define DIM  32
#define PAD  33      // odd pad
#define LSTR (NSEG * PAD)   // 693; 693 mod 32 = 21, coprime-ish spread
#define NREP 16      // LDS replicas to kill same-address atomic serialization
#define DV   0.5f
#define DD   3.0f
#define BATCH 8

// ws float layout:
//   counts: [BATCH][NSEG]        at 0                      (168 floats)
//   sums:   [BATCH][NSEG][DIM]   at BATCH*NSEG             (5376 floats)
//   vsum:   [BATCH][NSEG]        at BATCH*NSEG*(1+DIM)     (168 floats)
#define WS_SUM_OFF  (BATCH * NSEG)
#define WS_VS_OFF   (BATCH * NSEG + BATCH * NSEG * DIM)
#define WS_TOTAL_F  (BATCH * NSEG + BATCH * NSEG * DIM + BATCH * NSEG)

__global__ __launch_bounds__(256)
void k_sums(const float* __restrict__ emb, const int* __restrict__ seg,
            float* __restrict__ ws, int N) {
  __shared__ float s_sum[NREP * LSTR];    // 44.4 KB, 16 replicas
  __shared__ float s_cnt[NREP * NSEG];
  const int tid = threadIdx.x;
  const int b = blockIdx.y;
  for (int i = tid; i < NREP * LSTR; i += 256) s_sum[i] = 0.f;
  for (int i = tid; i < NREP * NSEG; i += 256) s_cnt[i] = 0.f;
  __syncthreads();

  const int rep = tid & (NREP - 1);
  const int rbs = rep * LSTR;
  const int rbc = rep * NSEG;

  const int n0 = blockIdx.x * 1024 + tid * 4;
  const size_t base = (size_t)b * DIM * N;
  const int4 s4 = *reinterpret_cast<const int4*>(seg + (size_t)b * N + n0);
  atomicAdd(&s_cnt[rbc + s4.x], 1.f);
  atomicAdd(&s_cnt[rbc + s4.y], 1.f);
  atomicAdd(&s_cnt[rbc + s4.z], 1.f);
  atomicAdd(&s_cnt[rbc + s4.w], 1.f);
  const int ax = rbs + s4.x * PAD, ay = rbs + s4.y * PAD;
  const int az = rbs + s4.z * PAD, aw = rbs + s4.w * PAD;
  #pragma unroll 8
  for (int d = 0; d < DIM; ++d) {
    const float4 e = *reinterpret_cast<const float4*>(emb + base + (size_t)d * N + n0);
    atomicAdd(&s_sum[ax + d], e.x);
    atomicAdd(&s_sum[ay + d], e.y);
    atomicAdd(&s_sum[az + d], e.z);
    atomicAdd(&s_sum[aw + d], e.w);
  }
  __syncthreads();
  float* gc = ws + b * NSEG;
  float* gs = ws + WS_SUM_OFF + b * NSEG * DIM;
  for (int i = tid; i < NSEG * DIM; i += 256) {
    const int s = i >> 5, d = i & 31;
    float v = 0.f;
    #pragma unroll
    for (int r = 0; r < NREP; ++r) v += s_sum[r * LSTR + s * PAD + d];
    atomicAdd(&gs[i], v);
  }
  if (tid < NSEG) {
    float c = 0.f;
    #pragma unroll
    for (int r = 0; r < NREP; ++r) c += s_cnt[r * NSEG + tid];
    atomicAdd(&gc[tid], c);
  }
}

__global__ __launch_bounds__(256)
void k_var(const float* __restrict__ emb, const int* __restrict__ seg,
           float* __restrict__ ws, int N) {
  __shared__ float s_m[LSTR];
  __shared__ float s_v[NREP * NSEG];
  const int tid = threadIdx.x;
  const int b = blockIdx.y;
  const float* gc = ws + b * NSEG;
  const float* gs = ws + WS_SUM_OFF + b * NSEG * DIM;
  for (int i = tid; i < NSEG * DIM; i += 256) {
    const int s = i >> 5, d = i & 31;
    s_m[s * PAD + d] = gs[i] / fmaxf(gc[s], 1.f);
  }
  for (int i = tid; i < NREP * NSEG; i += 256) s_v[i] = 0.f;
  __syncthreads();

  const int rep = tid & (NREP - 1);
  const int rbc = rep * NSEG;

  const int n0 = blockIdx.x * 1024 + tid * 4;
  const size_t base = (size_t)b * DIM * N;
  const int4 s4 = *reinterpret_cast<const int4*>(seg + (size_t)b * N + n0);
  const int ax = s4.x * PAD, ay = s4.y * PAD, az = s4.z * PAD, aw = s4.w * PAD;
  float q0 = 0.f, q1 = 0.f, q2 = 0.f, q3 = 0.f;
  #pragma unroll 8
  for (int d = 0; d < DIM; ++d) {
    const float4 e = *reinterpret_cast<const float4*>(emb + base + (size_t)d * N + n0);
    float t;
    t = e.x - s_m[ax + d]; q0 += t * t;
    t = e.y - s_m[ay + d]; q1 += t * t;
    t = e.z - s_m[az + d]; q2 += t * t;
    t = e.w - s_m[aw + d]; q3 += t * t;
  }
  if (s4.x > 0) { const float r = sqrtf(q0) - DV; if (r > 0.f) atomicAdd(&s_v[rbc + s4.x], r * r); }
  if (s4.y > 0) { const float r = sqrtf(q1) - DV; if (r > 0.f) atomicAdd(&s_v[rbc + s4.y], r * r); }
  if (s4.z > 0) { const float r = sqrtf(q2) - DV; if (r > 0.f) atomicAdd(&s_v[rbc + s4.z], r * r); }
  if (s4.w > 0) { const float r = sqrtf(q3) - DV; if (r > 0.f) atomicAdd(&s_v[rbc + s4.w], r * r); }
  __syncthreads();
  float* gv = ws + WS_VS_OFF + b * NSEG;
  if (tid < NSEG) {
    float c = 0.f;
    #pragma unroll
    for (int r = 0; r < NREP; ++r) c += s_v[r * NSEG + tid];
    atomicAdd(&gv[tid], c);
  }
}

__global__ __launch_bounds__(256)
void k_final(const float* __restrict__ ws, float* __restrict__ out) {
  __shared__ float s_m[NLBL * PAD];
  __shared__ float s_cnt[NSEG];
  __shared__ int   s_p[NLBL];
  __shared__ float s_var, s_dl;
  const int tid = threadIdx.x;
  float acc_v = 0.f, acc_d = 0.f;
  for (int b = 0; b < BATCH; ++b) {
    const float* gc = ws + b * NSEG;
    const float* gs = ws + WS_SUM_OFF + b * NSEG * DIM;
    const float* gv = ws + WS_VS_OFF + b * NSEG;
    __syncthreads();                       // protect reuse across batches
    if (tid < NSEG) s_cnt[tid] = gc[tid];
    if (tid == 0) { s_var = 0.f; s_dl = 0.f; }
    __syncthreads();
    for (int i = tid; i < NLBL * DIM; i += 256) {
      const int l = i >> 5, d = i & 31;    // l = 0..19 -> label l+1
      s_m[l * PAD + d] = gs[(l + 1) * DIM + d] / fmaxf(s_cnt[l + 1], 1.f);
    }
    if (tid < NLBL) s_p[tid] = (s_cnt[tid + 1] > 0.f) ? 1 : 0;
    if (tid < NLBL && s_cnt[tid + 1] > 0.f)
      atomicAdd(&s_var, gv[tid + 1] / s_cnt[tid + 1]);
    __syncthreads();                       // s_m / s_p ready
    float dl = 0.f;
    for (int p = tid; p < NLBL * NLBL; p += 256) {
      const int i = p / NLBL, j = p % NLBL;
      if (i != j && s_p[i] && s_p[j]) {
        float sq = 0.f;
        #pragma unroll
        for (int d = 0; d < DIM; ++d) {
          const float t = s_m[i * PAD + d] - s_m[j * PAD + d];
          sq += t * t;
        }
        const float r = DD - sqrtf(sq);
        if (r > 0.f) dl += r * r;
      }
    }
    atomicAdd(&s_dl, dl);
    __syncthreads();
    if (tid == 0) {
      float nl = 0.f;
      for (int l = 0; l < NLBL; ++l) nl += (float)s_p[l];
      acc_v += (nl > 0.f) ? (s_var / nl) : 0.f;
      acc_d += (nl > 1.f) ? (s_dl / fmaxf(nl * (nl - 1.f), 1.f) * 0.5f) : 0.f;
    }
  }
  if (tid == 0) {
    out[0] = acc_v / (float)BATCH;
    out[1] = acc_d / (float)BATCH;
    out[2] = 0.f;
  }
}

extern "C" void kernel_launch(void* const* d_in, const int* in_sizes, int n_in,
                              void* d_out, int out_size, void* d_ws, size_t ws_size,
                              hipStream_t stream) {
  const float* emb = (const float*)d_in[0];
  const int*   seg = (const int*)d_in[1];
  float* out = (float*)d_out;
  float* ws  = (float*)d_ws;
  const int N = in_sizes[1] / BATCH;   // 65536

  hipMemsetAsync(d_ws, 0, WS_TOTAL_F * sizeof(float), stream);

  dim3 grid(N / 1024, BATCH);
  k_sums<<<grid, 256, 0, stream>>>(emb, seg, ws, N);
  k_var <<<grid, 256, 0, stream>>>(emb, seg, ws, N);
  k_final<<<1, 256, 0, stream>>>(ws, out);
}

// Round 3
// 140.767 us; speedup vs baseline: 1.1344x; 1.1344x over previous
//
#include <hip/hip_runtime.h>

#define NSEG 21      // labels 0..20
#define NLBL 20
#define DIM  32
#define DCH  4       // d-chunks for k_sums
#define DPC  8       // dims per chunk
#define PADC (DPC + 1)
#define NREP 16      // LDS replicas
#define VREP 16      // global replicas for vsum flush
#define DV   0.5f
#define DD   3.0f
#define BATCH 8
#define SEGF 693     // per-batch canonical: [21 counts][672 sums, d-major: 21 + d*21 + s]

__global__ __launch_bounds__(256)
void k_sums(const float* __restrict__ emb, const int* __restrict__ seg,
            float* __restrict__ part, int N, int PARTS) {
  __shared__ float s_sum[NREP * NSEG * PADC];   // ~12 KB
  __shared__ float s_cnt[NREP * NSEG];
  const int tid = threadIdx.x;
  const int bx = blockIdx.x, b = blockIdx.y, dz = blockIdx.z;
  for (int i = tid; i < NREP * NSEG * PADC; i += 256) s_sum[i] = 0.f;
  for (int i = tid; i < NREP * NSEG; i += 256) s_cnt[i] = 0.f;
  __syncthreads();

  const int rep = tid & (NREP - 1);
  const int n0 = bx * 1024 + tid * 4;
  const int4 s4 = *reinterpret_cast<const int4*>(seg + (size_t)b * N + n0);
  if (dz == 0) {
    const int rb = rep * NSEG;
    atomicAdd(&s_cnt[rb + s4.x], 1.f);
    atomicAdd(&s_cnt[rb + s4.y], 1.f);
    atomicAdd(&s_cnt[rb + s4.z], 1.f);
    atomicAdd(&s_cnt[rb + s4.w], 1.f);
  }
  const int d0 = dz * DPC;
  const size_t base = (size_t)b * DIM * N + (size_t)d0 * N + n0;
  const int ax = (rep * NSEG + s4.x) * PADC;
  const int ay = (rep * NSEG + s4.y) * PADC;
  const int az = (rep * NSEG + s4.z) * PADC;
  const int aw = (rep * NSEG + s4.w) * PADC;
  #pragma unroll
  for (int dd = 0; dd < DPC; ++dd) {
    const float4 e = *reinterpret_cast<const float4*>(emb + base + (size_t)dd * N);
    atomicAdd(&s_sum[ax + dd], e.x);
    atomicAdd(&s_sum[ay + dd], e.y);
    atomicAdd(&s_sum[az + dd], e.z);
    atomicAdd(&s_sum[aw + dd], e.w);
  }
  __syncthreads();

  const bool excl = (PARTS == (int)gridDim.x);   // one writer per slice -> plain store
  const int slot = bx % PARTS;
  float* dst = part + ((size_t)b * PARTS + slot) * SEGF;
  for (int i = tid; i < NSEG * DPC; i += 256) {
    const int dd = i / NSEG, s = i - dd * NSEG;
    float v = 0.f;
    #pragma unroll
    for (int r = 0; r < NREP; ++r) v += s_sum[(r * NSEG + s) * PADC + dd];
    const int o = NSEG + (d0 + dd) * NSEG + s;
    if (excl) dst[o] = v; else atomicAdd(&dst[o], v);
  }
  if (dz == 0 && tid < NSEG) {
    float c = 0.f;
    #pragma unroll
    for (int r = 0; r < NREP; ++r) c += s_cnt[r * NSEG + tid];
    if (excl) dst[tid] = c; else atomicAdd(&dst[tid], c);
  }
}

__global__ __launch_bounds__(256)
void k_mid(const float* __restrict__ part, float* __restrict__ canon, int PARTS) {
  const int g = blockIdx.x * 256 + threadIdx.x;
  if (g >= BATCH * SEGF) return;
  const int b = g / SEGF, i = g - b * SEGF;
  float v = 0.f;
  for (int p = 0; p < PARTS; ++p)
    v += part[((size_t)b * PARTS + p) * SEGF + i];
  canon[b * SEGF + i] = v;
}

__global__ __launch_bounds__(256)
void k_var(const float* __restrict__ emb, const int* __restrict__ seg,
           const float* __restrict__ canon, float* __restrict__ vrep, int N) {
  __shared__ float s_m[NSEG * 33];
  __shared__ float s_c[NSEG];
  __shared__ float s_v[NREP * NSEG];
  const int tid = threadIdx.x;
  const int bx = blockIdx.x, b = blockIdx.y;
  const float* cb = canon + b * SEGF;
  if (tid < NSEG) s_c[tid] = fmaxf(cb[tid], 1.f);
  for (int i = tid; i < NREP * NSEG; i += 256) s_v[i] = 0.f;
  __syncthreads();
  for (int i = tid; i < DIM * NSEG; i += 256) {
    const int d = i / NSEG, s = i - d * NSEG;
    s_m[s * 33 + d] = cb[NSEG + i] / s_c[s];
  }
  __syncthreads();

  const int n = bx * 256 + tid;
  const int sl = seg[(size_t)b * N + n];
  const size_t base = (size_t)b * DIM * N + n;
  const int ml = sl * 33;
  float q = 0.f;
  #pragma unroll
  for (int d = 0; d < DIM; ++d) {
    const float e = emb[base + (size_t)d * N];
    const float t = e - s_m[ml + d];
    q += t * t;
  }
  if (sl > 0) {
    const float r = sqrtf(q) - DV;
    if (r > 0.f) atomicAdd(&s_v[(tid & (NREP - 1)) * NSEG + sl], r * r);
  }
  __syncthreads();
  if (tid < NSEG) {
    float v = 0.f;
    #pragma unroll
    for (int r = 0; r < NREP; ++r) v += s_v[r * NSEG + tid];
    atomicAdd(&vrep[((bx & (VREP - 1)) * BATCH + b) * NSEG + tid], v);
  }
}

__global__ __launch_bounds__(256)
void k_final(const float* __restrict__ canon, const float* __restrict__ vrep,
             float* __restrict__ out) {
  __shared__ float s_m[NLBL * 33];
  __shared__ float s_cnt[NSEG];
  __shared__ float s_vs[NSEG];
  __shared__ int   s_p[NLBL];
  __shared__ float s_dl;
  const int b = blockIdx.x;
  const int tid = threadIdx.x;
  const float* cb = canon + b * SEGF;
  if (tid < NSEG) {
    s_cnt[tid] = cb[tid];
    float v = 0.f;
    for (int r = 0; r < VREP; ++r) v += vrep[(r * BATCH + b) * NSEG + tid];
    s_vs[tid] = v;
  }
  if (tid == 0) s_dl = 0.f;
  __syncthreads();
  for (int i = tid; i < NLBL * DIM; i += 256) {
    const int l = i >> 5, d = i & 31;           // l -> label l+1
    s_m[l * 33 + d] = cb[NSEG + d * NSEG + (l + 1)] / fmaxf(s_cnt[l + 1], 1.f);
  }
  if (tid < NLBL) s_p[tid] = (s_cnt[tid + 1] > 0.f) ? 1 : 0;
  __syncthreads();
  float dl = 0.f;
  for (int p = tid; p < NLBL * NLBL; p += 256) {
    const int i = p / NLBL, j = p - (p / NLBL) * NLBL;
    if (i != j && s_p[i] && s_p[j]) {
      float sq = 0.f;
      #pragma unroll
      for (int d = 0; d < DIM; ++d) {
        const float t = s_m[i * 33 + d] - s_m[j * 33 + d];
        sq += t * t;
      }
      const float r = DD - sqrtf(sq);
      if (r > 0.f) dl += r * r;
    }
  }
  atomicAdd(&s_dl, dl);
  __syncthreads();
  if (tid == 0) {
    float nl = 0.f, var = 0.f;
    for (int l = 1; l <= NLBL; ++l)
      if (s_cnt[l] > 0.f) { nl += 1.f; var += s_vs[l] / s_cnt[l]; }
    const float vb = (nl > 0.f) ? var / nl : 0.f;
    const float db = (nl > 1.f) ? s_dl / fmaxf(nl * (nl - 1.f), 1.f) * 0.5f : 0.f;
    atomicAdd(&out[0], vb / (float)BATCH);
    atomicAdd(&out[1], db / (float)BATCH);
    // out[2] stays 0 from the memset
  }
}

extern "C" void kernel_launch(void* const* d_in, const int* in_sizes, int n_in,
                              void* d_out, int out_size, void* d_ws, size_t ws_size,
                              hipStream_t stream) {
  const float* emb = (const float*)d_in[0];
  const int*   seg = (const int*)d_in[1];
  float* out = (float*)d_out;
  float* ws  = (float*)d_ws;
  const int N = in_sizes[1] / BATCH;   // 65536
  const int NBX = N / 1024;            // 64

  // pick largest PARTS that fits ws: NBX (deterministic stores) > 8 > 1 (atomic fallback)
  int PARTS = NBX;
  auto need = [&](int p) {
    return ((size_t)BATCH * p * SEGF + (size_t)BATCH * SEGF +
            (size_t)VREP * BATCH * NSEG) * sizeof(float);
  };
  if (ws_size < need(PARTS)) PARTS = 8;
  if (ws_size < need(PARTS)) PARTS = 1;

  float* part  = ws;
  float* canon = part + (size_t)BATCH * PARTS * SEGF;
  float* vrep  = canon + BATCH * SEGF;

  if (PARTS != NBX)
    hipMemsetAsync(part, 0, (size_t)BATCH * PARTS * SEGF * sizeof(float), stream);
  hipMemsetAsync(vrep, 0, (size_t)VREP * BATCH * NSEG * sizeof(float), stream);
  hipMemsetAsync(d_out, 0, (size_t)out_size * sizeof(float), stream);

  k_sums <<<dim3(NBX, BATCH, DCH), 256, 0, stream>>>(emb, seg, part, N, PARTS);
  k_mid  <<<dim3((BATCH * SEGF + 255) / 256), 256, 0, stream>>>(part, canon, PARTS);
  k_var  <<<dim3(N / 256, BATCH), 256, 0, stream>>>(emb, seg, canon, vrep, N);
  k_final<<<dim3(BATCH), 256, 0, stream>>>(canon, vrep, out);
}